// Round 7
// baseline (53.359 us; speedup 1.0000x reference)
//
#include <hip/hip_runtime.h>
#include <hip/hip_bf16.h>

#define A_N 8
#define C_N 256
#define H_N 80
#define W_N 108
#define P_N (H_N * W_N)      // 8640
#define P4_N (P_N / 4)       // 2160 float4 per plane
#define O_N 7
#define MH 256               // mask H
#define MW 256               // mask W
#define OUT_HW 256

#define GSP  4               // channel split
#define CPG  (C_N / GSP)     // 64 channels per group

__device__ __forceinline__ float sigmoidf_(float zv) {
    return 1.0f / (1.0f + __expf(-zv));
}

// ---------------------------------------------------------------------------
// Split-K conv, m13-shaped access: thread = one float4 pixel-column, lanes
// consecutive in px4 -> 1KB contiguous per wave vmem instruction, unroll 8
// -> 8KB in flight per wave. Grid 270 x 256 = 69120 columns exact
// (8 agents x 4 ch-groups x 2160 px4).
//   part[a][g][o][p] = sum_{c in group g} w[o,c] * x[a,c,p]
// ---------------------------------------------------------------------------
__launch_bounds__(256)
__global__ void k_convp(const float* __restrict__ x, const float* __restrict__ w,
                        float* __restrict__ part)
{
    const int i   = blockIdx.x * 256 + threadIdx.x;   // column id, exact cover
    const int px4 = i % P4_N;
    const int ag  = i / P4_N;          // [0,32)
    const int a   = ag >> 2;
    const int g   = ag & 3;

    float4 acc[O_N];
    #pragma unroll
    for (int o = 0; o < O_N; ++o) acc[o] = make_float4(0.f, 0.f, 0.f, 0.f);

    const float4* xp = reinterpret_cast<const float4*>(x)
                     + (size_t)(a * C_N + g * CPG) * P4_N + px4;
    const float*  wp = w + g * CPG;

    #pragma unroll 8
    for (int cc = 0; cc < CPG; ++cc) {
        float4 v = xp[(size_t)cc * P4_N];
        #pragma unroll
        for (int o = 0; o < O_N; ++o) {
            float wv = wp[o * C_N + cc];
            acc[o].x = fmaf(wv, v.x, acc[o].x);
            acc[o].y = fmaf(wv, v.y, acc[o].y);
            acc[o].z = fmaf(wv, v.z, acc[o].z);
            acc[o].w = fmaf(wv, v.w, acc[o].w);
        }
    }

    float4* pp = reinterpret_cast<float4*>(part) + (size_t)(ag * O_N) * P4_N + px4;
    #pragma unroll
    for (int o = 0; o < O_N; ++o) pp[(size_t)o * P4_N] = acc[o];
}

// ---------------------------------------------------------------------------
// Finalize: z = sum_g part[g] + wsum*cm ; ssolo = sigmoid(z + b)
// cm = antialias triangle resize of car_masks with FIXED 7x5 tap window
// (out-of-triangle / out-of-image taps get weight 0; same normalization as
// jax.image.resize). Compile-time trip counts -> 35 independent loads.
// Grid 270 x 256 exact over (a,p).
// ---------------------------------------------------------------------------
__launch_bounds__(256)
__global__ void k_finalize(const float* __restrict__ part, const float* __restrict__ masks,
                           const float* __restrict__ w, const float* __restrict__ b,
                           float* __restrict__ z, float* __restrict__ ssolo)
{
    __shared__ float s_wsum[O_N];
    if (threadIdx.x < O_N) {
        const float4* wr = reinterpret_cast<const float4*>(w + threadIdx.x * C_N);
        float s = 0.0f;
        #pragma unroll 4
        for (int c4 = 0; c4 < C_N / 4; ++c4) { float4 v = wr[c4]; s += v.x + v.y + v.z + v.w; }
        s_wsum[threadIdx.x] = s;
    }
    __syncthreads();

    const int idx = blockIdx.x * 256 + threadIdx.x;   // < 69120 exact
    const int a = idx / P_N, p = idx - a * P_N;
    const int oy = p / W_N, ox = p - oy * W_N;

    const float ksy = 256.0f / 80.0f;
    const float ksx = 256.0f / 108.0f;
    const float rky = 0.3125f;           // 80/256 exact
    const float rkx = 0.421875f;         // 108/256 exact

    const float sfy = ((float)oy + 0.5f) * ksy - 0.5f;
    const float sfx = ((float)ox + 0.5f) * ksx - 0.5f;
    const int iyS = (int)ceilf(sfy - ksy);
    const int ixS = (int)ceilf(sfx - ksx);

    float wxv[5];
    float wxs = 0.0f;
    #pragma unroll
    for (int q = 0; q < 5; ++q) {
        const int ix = ixS + q;
        float wv = fmaxf(0.0f, 1.0f - fabsf(sfx - (float)ix) * rkx);
        wv = (ix >= 0 && ix < MW) ? wv : 0.0f;
        wxv[q] = wv;
        wxs += wv;
    }

    const float* mp = masks + (size_t)a * (MH * MW);
    float acc = 0.0f, wys = 0.0f;
    #pragma unroll
    for (int r = 0; r < 7; ++r) {
        const int iy = iyS + r;
        float wy = fmaxf(0.0f, 1.0f - fabsf(sfy - (float)iy) * rky);
        wy = (iy >= 0 && iy < MH) ? wy : 0.0f;
        wys += wy;
        const float* row = mp + min(max(iy, 0), MH - 1) * MW;
        float rs = 0.0f;
        #pragma unroll
        for (int q = 0; q < 5; ++q)
            rs = fmaf(wxv[q], row[min(max(ixS + q, 0), MW - 1)], rs);
        acc = fmaf(wy, rs, acc);
    }
    const float cmv = acc / (wys * wxs);

    // ---- combine the 4 channel-group partials ----
    #pragma unroll
    for (int o = 0; o < O_N; ++o) {
        float s = 0.0f;
        #pragma unroll
        for (int g = 0; g < GSP; ++g)
            s += part[(size_t)((a * GSP + g) * O_N + o) * P_N + p];
        const float zv = s + s_wsum[o] * cmv;
        z[(size_t)(a * O_N + o) * P_N + p]     = zv;
        ssolo[(size_t)(a * O_N + o) * P_N + p] = sigmoidf_(zv + b[o]);
    }
}

// ---------------------------------------------------------------------------
// Aggregation: per ego i, pixel p: saggr = sigmoid(b + sum_j adj[i,j]!=0 ?
//              zero-padded-bilinear(z[j], rel[i,j] @ [u,v,1]) : 0)
// z planes total 1.9 MB — L2-resident gathers. 1080 blocks x 64.
// ---------------------------------------------------------------------------
__launch_bounds__(64)
__global__ void k_aggr(const float* __restrict__ z, const float* __restrict__ rel,
                       const int* __restrict__ adj, const float* __restrict__ b,
                       float* __restrict__ saggr)
{
    const int i = blockIdx.x / 135;
    const int p = (blockIdx.x - i * 135) * 64 + threadIdx.x;
    const int vy = p / W_N, ux = p - vy * W_N;
    const float fu = (float)ux, fv = (float)vy;

    float acc[O_N];
    #pragma unroll
    for (int o = 0; o < O_N; ++o) acc[o] = b[o];

    for (int j = 0; j < A_N; ++j) {
        if (adj[i * A_N + j] == 0) continue;
        const float* M = rel + (i * A_N + j) * 6;
        float sx = M[0] * fu + M[1] * fv + M[2];
        float sy = M[3] * fu + M[4] * fv + M[5];
        if (!(sx > -1.0f && sx < (float)W_N && sy > -1.0f && sy < (float)H_N)) continue;
        float x0f = floorf(sx), y0f = floorf(sy);
        float wx = sx - x0f, wy = sy - y0f;
        int x0 = (int)x0f, y0 = (int)y0f;
        int x1 = x0 + 1,  y1 = y0 + 1;
        float w00 = (1.0f - wy) * (1.0f - wx), w01 = (1.0f - wy) * wx;
        float w10 = wy * (1.0f - wx),          w11 = wy * wx;
        if (x0 < 0)    { w00 = 0.0f; w10 = 0.0f; x0 = 0; }
        if (x1 >= W_N) { w01 = 0.0f; w11 = 0.0f; x1 = W_N - 1; }
        if (y0 < 0)    { w00 = 0.0f; w01 = 0.0f; y0 = 0; }
        if (y1 >= H_N) { w10 = 0.0f; w11 = 0.0f; y1 = H_N - 1; }
        const int i00 = y0 * W_N + x0, i01 = y0 * W_N + x1;
        const int i10 = y1 * W_N + x0, i11 = y1 * W_N + x1;
        const float* zj = z + j * O_N * P_N;
        #pragma unroll
        for (int o = 0; o < O_N; ++o) {
            const float* zp = zj + o * P_N;
            acc[o] += w00 * zp[i00] + w01 * zp[i01] + w10 * zp[i10] + w11 * zp[i11];
        }
    }
    const int ob = i * O_N * P_N + p;
    #pragma unroll
    for (int o = 0; o < O_N; ++o) saggr[ob + o * P_N] = sigmoidf_(acc[o]);
}

// ---------------------------------------------------------------------------
// Upsample: align_corners=True bilinear 80x108 -> 256x256, f32 out.
// 4 px/thread -> float4 stores; 7168 blocks x 256 exact.
// Output layout: [solo(8,7,256,256), aggr(8,7,256,256)] flat f32.
// ---------------------------------------------------------------------------
__launch_bounds__(256)
__global__ void k_upsample(const float* __restrict__ ssolo, const float* __restrict__ saggr,
                           float* __restrict__ out)
{
    const int idx = blockIdx.x * 256 + threadIdx.x;   // quad index
    int k = idx;
    const int oxq = k & 63;   k >>= 6;
    const int oy  = k & 255;  k >>= 8;
    const int o   = k % O_N;  k /= O_N;
    const int a   = k & 7;    k >>= 3;
    const int t   = k;        // 0 = solo, 1 = aggr

    const float* src = (t == 0 ? ssolo : saggr) + (a * O_N + o) * P_N;
    float syf = (float)oy * (79.0f / 255.0f);
    int y0 = (int)syf; y0 = min(y0, H_N - 2);
    float wy = syf - (float)y0;
    const float* r0 = src + y0 * W_N;
    const float* r1 = r0 + W_N;

    float res[4];
    #pragma unroll
    for (int q = 0; q < 4; ++q) {
        int ox = oxq * 4 + q;
        float sxf = (float)ox * (107.0f / 255.0f);
        int x0 = (int)sxf; x0 = min(x0, W_N - 2);
        float wx = sxf - (float)x0;
        float c0 = r0[x0]     * (1.0f - wy) + r1[x0]     * wy;
        float c1 = r0[x0 + 1] * (1.0f - wy) + r1[x0 + 1] * wy;
        res[q] = c0 * (1.0f - wx) + c1 * wx;
    }
    *reinterpret_cast<float4*>(out + (size_t)idx * 4) =
        make_float4(res[0], res[1], res[2], res[3]);
}

// ---------------------------------------------------------------------------
extern "C" void kernel_launch(void* const* d_in, const int* in_sizes, int n_in,
                              void* d_out, int out_size, void* d_ws, size_t ws_size,
                              hipStream_t stream)
{
    (void)in_sizes; (void)n_in; (void)out_size; (void)ws_size;
    const float* x    = (const float*)d_in[0];
    const float* rel  = (const float*)d_in[1];
    const int*   adj  = (const int*)d_in[2];
    const float* cmsk = (const float*)d_in[3];
    const float* wcls = (const float*)d_in[4];
    const float* bcls = (const float*)d_in[5];
    float* out = (float*)d_out;   // reference output dtype is float32

    float* ws    = (float*)d_ws;
    float* part  = ws;                          // 4*8*7*8640 = 1,935,360 f32 (7.7 MB)
    float* z     = part  + GSP * A_N * O_N * P_N;
    float* ssolo = z     + A_N * O_N * P_N;
    float* saggr = ssolo + A_N * O_N * P_N;     // total ~13.6 MB

    k_convp   <<<270, 256, 0, stream>>>(x, wcls, part);
    k_finalize<<<270, 256, 0, stream>>>(part, cmsk, wcls, bcls, z, ssolo);
    k_aggr    <<<1080, 64, 0, stream>>>(z, rel, adj, bcls, saggr);
    k_upsample<<<7168, 256, 0, stream>>>(ssolo, saggr, out);
}

// Round 8
// 46.332 us; speedup vs baseline: 1.1516x; 1.1516x over previous
//
#include <hip/hip_runtime.h>
#include <hip/hip_bf16.h>

#define A_N 8
#define C_N 256
#define H_N 80
#define W_N 108
#define P_N (H_N * W_N)      // 8640
#define P4_N (P_N / 4)       // 2160 float4 columns per plane
#define O_N 7
#define MH 256
#define MW 256
#define OUT_HW 256
#define TPA 34               // 64-px4 tiles per agent (34*64 = 2176 >= 2160)

__device__ __forceinline__ float sigmoidf_(float zv) {
    return 1.0f / (1.0f + __expf(-zv));
}

// ---------------------------------------------------------------------------
// Fused resize + conv + epilogue.
// Grid 8*34 = 272 blocks x 256 thr. Block = one 64-px4 tile (256 px) of one
// agent. Wave wq (of 4) handles channel quarter [wq*64, wq*64+64).
// Explicit double-buffered 8-deep float4 load batches keep 8KB in flight per
// wave (the r7 failure was ~1 load in flight). cm is folded into the FMA
// input ( acc += w*(x+cm) ) — exact reference structure, no wsum needed.
// ---------------------------------------------------------------------------
__launch_bounds__(256)
__global__ void k_conv(const float* __restrict__ x, const float* __restrict__ masks,
                       const float* __restrict__ w, const float* __restrict__ b,
                       float* __restrict__ z, float* __restrict__ ssolo)
{
    __shared__ float4 s_red[4][64][O_N];   // 28 KB
    __shared__ float  s_cm[256];

    const int tid = threadIdx.x;
    const int bi  = blockIdx.x;
    const int a   = bi / TPA;
    const int t   = bi - a * TPA;

    // ---- prologue: antialias triangle resize (jax.image.resize semantics),
    //      fixed 7x5 window, 35 independent L2 loads per thread ----
    {
        const int ppx = t * 256 + tid;
        const int pc  = min(ppx, P_N - 1);
        const int oy = pc / W_N, ox = pc - oy * W_N;
        const float ksy = 256.0f / 80.0f;
        const float ksx = 256.0f / 108.0f;
        const float rky = 0.3125f;          // 80/256 exact
        const float rkx = 0.421875f;        // 108/256 exact
        const float sfy = ((float)oy + 0.5f) * ksy - 0.5f;
        const float sfx = ((float)ox + 0.5f) * ksx - 0.5f;
        const int iyS = (int)ceilf(sfy - ksy);
        const int ixS = (int)ceilf(sfx - ksx);

        float wxv[5];
        float wxs = 0.0f;
        #pragma unroll
        for (int q = 0; q < 5; ++q) {
            const int ix = ixS + q;
            float wv = fmaxf(0.0f, 1.0f - fabsf(sfx - (float)ix) * rkx);
            wv = (ix >= 0 && ix < MW) ? wv : 0.0f;
            wxv[q] = wv;
            wxs += wv;
        }
        const float* mp = masks + (size_t)a * (MH * MW);
        float acc = 0.0f, wys = 0.0f;
        #pragma unroll
        for (int r = 0; r < 7; ++r) {
            const int iy = iyS + r;
            float wy = fmaxf(0.0f, 1.0f - fabsf(sfy - (float)iy) * rky);
            wy = (iy >= 0 && iy < MH) ? wy : 0.0f;
            wys += wy;
            const float* row = mp + min(max(iy, 0), MH - 1) * MW;
            float rs = 0.0f;
            #pragma unroll
            for (int q = 0; q < 5; ++q)
                rs = fmaf(wxv[q], row[min(max(ixS + q, 0), MW - 1)], rs);
            acc = fmaf(wy, rs, acc);
        }
        s_cm[tid] = acc / (wys * wxs);
    }
    __syncthreads();

    // ---- conv main loop ----
    const int wq   = tid >> 6;              // channel quarter
    const int lane = tid & 63;              // px4 within tile
    const int px4  = t * 64 + lane;
    const int px4c = min(px4, P4_N - 1);

    const float4 cm4 = make_float4(s_cm[lane * 4], s_cm[lane * 4 + 1],
                                   s_cm[lane * 4 + 2], s_cm[lane * 4 + 3]);

    const float4* xp = reinterpret_cast<const float4*>(x)
                     + (size_t)(a * C_N + wq * 64) * P4_N + px4c;
    const float* wp = w + wq * 64;          // wave-uniform -> scalar loads

    float4 acc[O_N];
    #pragma unroll
    for (int o = 0; o < O_N; ++o) acc[o] = make_float4(0.f, 0.f, 0.f, 0.f);

    float4 va[8], vb[8];

#define LOADB(buf, cb)                                            \
    _Pragma("unroll")                                             \
    for (int u = 0; u < 8; ++u) buf[u] = xp[(size_t)((cb) + u) * P4_N];

#define COMPB(buf, cb)                                            \
    _Pragma("unroll")                                             \
    for (int u = 0; u < 8; ++u) {                                 \
        float4 v = buf[u];                                        \
        v.x += cm4.x; v.y += cm4.y; v.z += cm4.z; v.w += cm4.w;   \
        _Pragma("unroll")                                         \
        for (int o = 0; o < O_N; ++o) {                           \
            const float wv = wp[o * C_N + (cb) + u];              \
            acc[o].x = fmaf(wv, v.x, acc[o].x);                   \
            acc[o].y = fmaf(wv, v.y, acc[o].y);                   \
            acc[o].z = fmaf(wv, v.z, acc[o].z);                   \
            acc[o].w = fmaf(wv, v.w, acc[o].w);                   \
        }                                                         \
    }

    LOADB(va, 0)
    LOADB(vb, 8)   COMPB(va, 0)
    LOADB(va, 16)  COMPB(vb, 8)
    LOADB(vb, 24)  COMPB(va, 16)
    LOADB(va, 32)  COMPB(vb, 24)
    LOADB(vb, 40)  COMPB(va, 32)
    LOADB(va, 48)  COMPB(vb, 40)
    LOADB(vb, 56)  COMPB(va, 48)
    COMPB(vb, 56)
#undef LOADB
#undef COMPB

    #pragma unroll
    for (int o = 0; o < O_N; ++o) s_red[wq][lane][o] = acc[o];
    __syncthreads();

    // ---- epilogue: sum 4 quarters, bias+sigmoid, float4 stores ----
    for (int pair = tid; pair < 64 * O_N; pair += 256) {
        const int pl = pair & 63;
        const int o  = pair >> 6;
        const int pg = t * 64 + pl;
        if (pg >= P4_N) continue;
        const float4 s0 = s_red[0][pl][o];
        const float4 s1 = s_red[1][pl][o];
        const float4 s2 = s_red[2][pl][o];
        const float4 s3 = s_red[3][pl][o];
        float4 zv;
        zv.x = s0.x + s1.x + s2.x + s3.x;
        zv.y = s0.y + s1.y + s2.y + s3.y;
        zv.z = s0.z + s1.z + s2.z + s3.z;
        zv.w = s0.w + s1.w + s2.w + s3.w;
        const float bo = b[o];
        const size_t ob = (size_t)(a * O_N + o) * P4_N + pg;
        reinterpret_cast<float4*>(z)[ob] = zv;
        float4 sv;
        sv.x = sigmoidf_(zv.x + bo);
        sv.y = sigmoidf_(zv.y + bo);
        sv.z = sigmoidf_(zv.z + bo);
        sv.w = sigmoidf_(zv.w + bo);
        reinterpret_cast<float4*>(ssolo)[ob] = sv;
    }
}

// ---------------------------------------------------------------------------
// Aggregation: per ego i, pixel p: saggr = sigmoid(b + sum_j adj[i,j]!=0 ?
//              zero-padded-bilinear(z[j], rel[i,j] @ [u,v,1]) : 0)
// z planes total 1.9 MB — L2-resident gathers. 1080 blocks x 64.
// ---------------------------------------------------------------------------
__launch_bounds__(64)
__global__ void k_aggr(const float* __restrict__ z, const float* __restrict__ rel,
                       const int* __restrict__ adj, const float* __restrict__ b,
                       float* __restrict__ saggr)
{
    const int i = blockIdx.x / 135;
    const int p = (blockIdx.x - i * 135) * 64 + threadIdx.x;
    const int vy = p / W_N, ux = p - vy * W_N;
    const float fu = (float)ux, fv = (float)vy;

    float acc[O_N];
    #pragma unroll
    for (int o = 0; o < O_N; ++o) acc[o] = b[o];

    for (int j = 0; j < A_N; ++j) {
        if (adj[i * A_N + j] == 0) continue;
        const float* M = rel + (i * A_N + j) * 6;
        float sx = M[0] * fu + M[1] * fv + M[2];
        float sy = M[3] * fu + M[4] * fv + M[5];
        if (!(sx > -1.0f && sx < (float)W_N && sy > -1.0f && sy < (float)H_N)) continue;
        float x0f = floorf(sx), y0f = floorf(sy);
        float wx = sx - x0f, wy = sy - y0f;
        int x0 = (int)x0f, y0 = (int)y0f;
        int x1 = x0 + 1,  y1 = y0 + 1;
        float w00 = (1.0f - wy) * (1.0f - wx), w01 = (1.0f - wy) * wx;
        float w10 = wy * (1.0f - wx),          w11 = wy * wx;
        if (x0 < 0)    { w00 = 0.0f; w10 = 0.0f; x0 = 0; }
        if (x1 >= W_N) { w01 = 0.0f; w11 = 0.0f; x1 = W_N - 1; }
        if (y0 < 0)    { w00 = 0.0f; w01 = 0.0f; y0 = 0; }
        if (y1 >= H_N) { w10 = 0.0f; w11 = 0.0f; y1 = H_N - 1; }
        const int i00 = y0 * W_N + x0, i01 = y0 * W_N + x1;
        const int i10 = y1 * W_N + x0, i11 = y1 * W_N + x1;
        const float* zj = z + j * O_N * P_N;
        #pragma unroll
        for (int o = 0; o < O_N; ++o) {
            const float* zp = zj + o * P_N;
            acc[o] += w00 * zp[i00] + w01 * zp[i01] + w10 * zp[i10] + w11 * zp[i11];
        }
    }
    const int ob = i * O_N * P_N + p;
    #pragma unroll
    for (int o = 0; o < O_N; ++o) saggr[ob + o * P_N] = sigmoidf_(acc[o]);
}

// ---------------------------------------------------------------------------
// Upsample: align_corners=True bilinear 80x108 -> 256x256, f32 out.
// 4 px/thread -> float4 stores; 7168 blocks x 256 exact.
// Output layout: [solo(8,7,256,256), aggr(8,7,256,256)] flat f32.
// ---------------------------------------------------------------------------
__launch_bounds__(256)
__global__ void k_upsample(const float* __restrict__ ssolo, const float* __restrict__ saggr,
                           float* __restrict__ out)
{
    const int idx = blockIdx.x * 256 + threadIdx.x;   // quad index
    int k = idx;
    const int oxq = k & 63;   k >>= 6;
    const int oy  = k & 255;  k >>= 8;
    const int o   = k % O_N;  k /= O_N;
    const int a   = k & 7;    k >>= 3;
    const int t   = k;        // 0 = solo, 1 = aggr

    const float* src = (t == 0 ? ssolo : saggr) + (a * O_N + o) * P_N;
    float syf = (float)oy * (79.0f / 255.0f);
    int y0 = (int)syf; y0 = min(y0, H_N - 2);
    float wy = syf - (float)y0;
    const float* r0 = src + y0 * W_N;
    const float* r1 = r0 + W_N;

    float res[4];
    #pragma unroll
    for (int q = 0; q < 4; ++q) {
        int ox = oxq * 4 + q;
        float sxf = (float)ox * (107.0f / 255.0f);
        int x0 = (int)sxf; x0 = min(x0, W_N - 2);
        float wx = sxf - (float)x0;
        float c0 = r0[x0]     * (1.0f - wy) + r1[x0]     * wy;
        float c1 = r0[x0 + 1] * (1.0f - wy) + r1[x0 + 1] * wy;
        res[q] = c0 * (1.0f - wx) + c1 * wx;
    }
    *reinterpret_cast<float4*>(out + (size_t)idx * 4) =
        make_float4(res[0], res[1], res[2], res[3]);
}

// ---------------------------------------------------------------------------
extern "C" void kernel_launch(void* const* d_in, const int* in_sizes, int n_in,
                              void* d_out, int out_size, void* d_ws, size_t ws_size,
                              hipStream_t stream)
{
    (void)in_sizes; (void)n_in; (void)out_size; (void)ws_size;
    const float* x    = (const float*)d_in[0];
    const float* rel  = (const float*)d_in[1];
    const int*   adj  = (const int*)d_in[2];
    const float* cmsk = (const float*)d_in[3];
    const float* wcls = (const float*)d_in[4];
    const float* bcls = (const float*)d_in[5];
    float* out = (float*)d_out;   // reference output dtype is float32

    float* ws    = (float*)d_ws;
    float* z     = ws;                          // 8*7*8640 = 483,840 f32
    float* ssolo = z     + A_N * O_N * P_N;
    float* saggr = ssolo + A_N * O_N * P_N;     // total ~5.8 MB

    k_conv    <<<A_N * TPA, 256, 0, stream>>>(x, cmsk, wcls, bcls, z, ssolo);
    k_aggr    <<<1080, 64, 0, stream>>>(z, rel, adj, bcls, saggr);
    k_upsample<<<7168, 256, 0, stream>>>(ssolo, saggr, out);
}